// Round 3
// baseline (157.770 us; speedup 1.0000x reference)
//
#include <hip/hip_runtime.h>
#include <hip/hip_bf16.h>
#include <math.h>

#define N 4096
#define D 1024
#define NINST 8
#define NGROUP (N / NINST)
#define ALPHA 20.0f
#define MARGIN 0.5f

typedef __attribute__((ext_vector_type(8))) short bf16x8;
typedef __attribute__((ext_vector_type(4))) float f32x4;

__device__ __forceinline__ unsigned fkey(float f) {
    int b = __float_as_int(f);
    return (b >= 0) ? ((unsigned)b | 0x80000000u) : ~(unsigned)b;
}
__device__ __forceinline__ float fdec(unsigned u) {
    int b = (u & 0x80000000u) ? (int)(u ^ 0x80000000u) : ~(int)u;
    return __int_as_float(b);
}

// stable fast softplus: log1p(exp(x)) = max(x,0) + log(1 + exp(-|x|))
__device__ __forceinline__ float softplus(float x) {
    float z = __expf(-fabsf(x));
    return fmaxf(x, 0.0f) + __logf(1.0f + z);
}

// async global -> LDS, 16 bytes per lane (lds dest: wave-uniform base + lane*16)
__device__ __forceinline__ void gld16(const void* g, void* l) {
    __builtin_amdgcn_global_load_lds(
        (const __attribute__((address_space(1))) void*)g,
        (__attribute__((address_space(3))) void*)l, 16, 0, 0);
}

// ---------------- K1: row L2-normalize, fp32 -> bf16 + inv_norm ----------------
__global__ __launch_bounds__(256) void k_norm(const float* __restrict__ in,
                                              ushort* __restrict__ xn,
                                              float* __restrict__ inv_norm) {
    int row = blockIdx.x;
    int t = threadIdx.x;
    const float4* p = (const float4*)(in + (size_t)row * D);
    float4 v = p[t];                       // 256 threads * 4 = 1024
    float ss = v.x * v.x + v.y * v.y + v.z * v.z + v.w * v.w;
    int lane = t & 63, wid = t >> 6;
    #pragma unroll
    for (int off = 1; off < 64; off <<= 1) ss += __shfl_xor(ss, off);
    __shared__ float sred[4];
    if (lane == 0) sred[wid] = ss;
    __syncthreads();
    float tot = sred[0] + sred[1] + sred[2] + sred[3];
    float inv = 1.0f / sqrtf(tot);
    if (t == 0) inv_norm[row] = inv;
    ushort4 o;
    __hip_bfloat16 h;
    h = __float2bfloat16(v.x * inv); o.x = *(ushort*)&h;
    h = __float2bfloat16(v.y * inv); o.y = *(ushort*)&h;
    h = __float2bfloat16(v.z * inv); o.z = *(ushort*)&h;
    h = __float2bfloat16(v.w * inv); o.w = *(ushort*)&h;
    ((ushort4*)(xn + (size_t)row * D))[t] = o;
}

// ---------------- K2: exact fp32 positive sims per group (8x8 Gram) ----------------
// 256 threads: 64 pairs x 4 D-slices, shfl-reduce across slices.
__global__ __launch_bounds__(256) void k_pos(const float* __restrict__ in,
                                             const float* __restrict__ inv_norm,
                                             float* __restrict__ pos_sims,
                                             float* __restrict__ min_pos) {
    int g = blockIdx.x;
    int t = threadIdx.x;
    int pair = t >> 2;          // 0..63
    int a = pair >> 3, b = pair & 7;
    int slice = t & 3;
    int ra = g * 8 + a, rb = g * 8 + b;
    const float4* pa = (const float4*)(in + (size_t)ra * D) + slice * 64;
    const float4* pb = (const float4*)(in + (size_t)rb * D) + slice * 64;
    float s = 0.f;
    #pragma unroll 8
    for (int i = 0; i < 64; ++i) {
        float4 x = pa[i], y = pb[i];
        s += x.x * y.x + x.y * y.y + x.z * y.z + x.w * y.w;
    }
    s += __shfl_xor(s, 1);
    s += __shfl_xor(s, 2);
    float sim = s * inv_norm[ra] * inv_norm[rb];
    __shared__ float sg[8][8];
    if (slice == 0) sg[a][b] = sim;
    __syncthreads();
    if (t < 8) {
        float mn = 1e30f;
        int idx = 0;
        #pragma unroll
        for (int b2 = 0; b2 < 8; ++b2) {
            if (b2 == t) continue;
            float v = sg[t][b2];
            mn = fminf(mn, v);
            pos_sims[(size_t)(g * 8 + t) * 8 + idx] = v;
            ++idx;
        }
        min_pos[g * 8 + t] = mn;
    }
}

// ---------------- K3: bf16 MFMA sim tiles (double-buffered LDS, 2-phase) ----------------
// grid (32, 32); block 256 = 4 waves in 2x2; 128x128 tile per block; BK=32.
__global__ __launch_bounds__(256) void k_neg(const ushort* __restrict__ xn,
                                             const float* __restrict__ min_pos,
                                             float* __restrict__ sum_part,
                                             int* __restrict__ cnt_part,
                                             float* __restrict__ max_part,
                                             unsigned* __restrict__ gmax) {
    __shared__ ushort sA[2][128 * 32];   // [buf][row][k] row-major
    __shared__ ushort sB[2][128 * 32];
    __shared__ float sMin[128];

    int rt = blockIdx.y, ct = blockIdx.x;
    int R0 = rt * 128, C0 = ct * 128;
    int t = threadIdx.x, lane = t & 63, wid = t >> 6;
    int wr = wid >> 1, wc = wid & 1;

    if (t < 128) sMin[t] = min_pos[R0 + t];

    // staging: thread t loads 8 bf16 (16B): row = t>>2 (+64 second issue),
    // k-offset = (t&3)*8. LDS dest is wave-uniform base + lane*16.
    int srow = t >> 2;
    int skoff = (t & 3) * 8;
    const ushort* gA0 = xn + (size_t)(R0 + srow) * D + skoff;
    const ushort* gA1 = xn + (size_t)(R0 + 64 + srow) * D + skoff;
    const ushort* gB0 = xn + (size_t)(C0 + srow) * D + skoff;
    const ushort* gB1 = xn + (size_t)(C0 + 64 + srow) * D + skoff;
    unsigned wbase = (unsigned)wid * 1024;   // 64 lanes * 16B per wave

    int lrow = lane & 15;
    int kgrp = lane >> 4;    // 0..3 -> k-octet

    f32x4 zero = {0.f, 0.f, 0.f, 0.f};
    f32x4 acc[4][4];
    #pragma unroll
    for (int m = 0; m < 4; ++m)
        #pragma unroll
        for (int n = 0; n < 4; ++n) acc[m][n] = zero;

    #define STAGE(buf, k0)                                        \
        do {                                                      \
            char* lA_ = (char*)sA[buf];                           \
            char* lB_ = (char*)sB[buf];                           \
            gld16(gA0 + (k0), lA_ + wbase);                       \
            gld16(gA1 + (k0), lA_ + 4096 + wbase);                \
            gld16(gB0 + (k0), lB_ + wbase);                       \
            gld16(gB1 + (k0), lB_ + 4096 + wbase);                \
        } while (0)

    STAGE(0, 0);
    __syncthreads();           // drain tile-0 loads; all waves synced

    int cur = 0;
    for (int it = 0; it < 32; ++it) {
        if (it + 1 < 32) STAGE(cur ^ 1, (it + 1) * 32);   // prefetch next tile

        const ushort* fA = sA[cur] + (size_t)(wr * 64 + lrow) * 32 + kgrp * 8;
        const ushort* fB = sB[cur] + (size_t)(wc * 64 + lrow) * 32 + kgrp * 8;
        bf16x8 a[4], b[4];
        #pragma unroll
        for (int m = 0; m < 4; ++m)
            a[m] = *(const bf16x8*)(fA + (size_t)m * 16 * 32);
        #pragma unroll
        for (int n = 0; n < 4; ++n)
            b[n] = *(const bf16x8*)(fB + (size_t)n * 16 * 32);
        #pragma unroll
        for (int m = 0; m < 4; ++m)
            #pragma unroll
            for (int n = 0; n < 4; ++n)
                acc[m][n] = __builtin_amdgcn_mfma_f32_16x16x32_bf16(a[m], b[n], acc[m][n], 0, 0, 0);

        __syncthreads();       // drains prefetch loads (they flew under the MFMAs)
        cur ^= 1;
    }
    #undef STAGE

    // epilogue: per-row negative stats + global max; partials stored [row][64]
    float allmax = -1e30f;
    int pc = ct * 2 + wc;
    int cbase = C0 + wc * 64;
    #pragma unroll
    for (int m = 0; m < 4; ++m) {
        #pragma unroll
        for (int reg = 0; reg < 4; ++reg) {
            int lr = wr * 64 + m * 16 + kgrp * 4 + reg;   // local row in [0,128)
            int grow = R0 + lr;
            float th = sMin[lr] - 0.05f;
            int gi = grow >> 3;
            float rs = 0.f, rm = -1e30f;
            int rc = 0;
            #pragma unroll
            for (int n = 0; n < 4; ++n) {
                int gcol = cbase + n * 16 + lrow;
                float s = acc[m][n][reg];
                allmax = fmaxf(allmax, s);
                if ((gcol >> 3) != gi) {
                    rm = fmaxf(rm, s);
                    if (s > th) { rs += softplus(ALPHA * (s - MARGIN)); rc += 1; }
                }
            }
            // reduce across the 16 col-lanes (same kgrp group)
            #pragma unroll
            for (int off = 1; off < 16; off <<= 1) {
                rs += __shfl_xor(rs, off);
                rc += __shfl_xor(rc, off);
                rm = fmaxf(rm, __shfl_xor(rm, off));
            }
            if (lrow == 0) {
                sum_part[(size_t)grow * 64 + pc] = rs;
                cnt_part[(size_t)grow * 64 + pc] = rc;
                max_part[(size_t)grow * 64 + pc] = rm;
            }
        }
    }
    #pragma unroll
    for (int off = 1; off < 64; off <<= 1) allmax = fmaxf(allmax, __shfl_xor(allmax, off));
    if (lane == 0) atomicMax(gmax, fkey(allmax));
}

// ---------------- K4a: per-row combine (64 lanes per row, coalesced partials) ----------------
__global__ __launch_bounds__(256) void k_row(const float* __restrict__ sum_part,
                                             const int* __restrict__ cnt_part,
                                             const float* __restrict__ max_part,
                                             const float* __restrict__ pos_sims,
                                             const float* __restrict__ min_pos,
                                             const unsigned* __restrict__ gmax,
                                             float* __restrict__ row_loss) {
    int row = blockIdx.x * 4 + (threadIdx.x >> 6);
    int lane = threadIdx.x & 63;
    float ns = sum_part[(size_t)row * 64 + lane];
    int nc = cnt_part[(size_t)row * 64 + lane];
    float nm = max_part[(size_t)row * 64 + lane];
    #pragma unroll
    for (int off = 1; off < 64; off <<= 1) {
        ns += __shfl_xor(ns, off);
        nc += __shfl_xor(nc, off);
        nm = fmaxf(nm, __shfl_xor(nm, off));
    }
    if (lane == 0) {
        float base = fmaxf(fdec(*gmax) - 0.1f, MARGIN + 0.2f);
        float neg_loss = (nc > 0) ? ns / (float)nc : softplus(ALPHA * (nm - MARGIN));
        float ps = 0.f;
        int pcnt = 0;
        float mn = min_pos[row];
        #pragma unroll
        for (int i = 0; i < NINST - 1; ++i) {
            float s = pos_sims[(size_t)row * 8 + i];
            if (s < base) { ps += softplus(-2.0f * (s - MARGIN)); pcnt++; }
        }
        float pos_loss = (pcnt > 0) ? ps / (float)pcnt : softplus(-2.0f * (mn - MARGIN));
        row_loss[row] = pos_loss + neg_loss;
    }
}

// ---------------- K4b: deterministic mean ----------------
__global__ __launch_bounds__(256) void k_final(const float* __restrict__ row_loss,
                                               float* __restrict__ out) {
    __shared__ float sred[256];
    int t = threadIdx.x;
    float s = 0.f;
    for (int i = t; i < N; i += 256) s += row_loss[i];
    sred[t] = s;
    __syncthreads();
    for (int off = 128; off; off >>= 1) {
        if (t < off) sred[t] += sred[t + off];
        __syncthreads();
    }
    if (t == 0) out[0] = sred[0] / (float)N;
}

extern "C" void kernel_launch(void* const* d_in, const int* in_sizes, int n_in,
                              void* d_out, int out_size, void* d_ws, size_t ws_size,
                              hipStream_t stream) {
    const float* in = (const float*)d_in[0];
    float* out = (float*)d_out;

    char* ws = (char*)d_ws;
    ushort*  xn       = (ushort*)(ws);                          // 8 MB
    float*   inv_norm = (float*)(ws + 8388608);                 // 16 KB
    float*   min_pos  = (float*)(ws + 8388608 + 16384);         // 16 KB
    float*   pos_sims = (float*)(ws + 8388608 + 32768);         // 128 KB
    float*   sum_part = (float*)(ws + 8388608 + 32768 + 131072);            // 1 MB
    float*   max_part = (float*)(ws + 8388608 + 32768 + 131072 + 1048576);  // 1 MB
    int*     cnt_part = (int*)  (ws + 8388608 + 32768 + 131072 + 2097152);  // 1 MB
    float*   row_loss = (float*)(ws + 8388608 + 32768 + 131072 + 3145728);  // 16 KB
    unsigned* gmax    = (unsigned*)(ws + 8388608 + 32768 + 131072 + 3145728 + 16384);

    hipMemsetAsync(gmax, 0, sizeof(unsigned), stream);

    k_norm<<<N, 256, 0, stream>>>(in, xn, inv_norm);
    k_pos<<<NGROUP, 256, 0, stream>>>(in, inv_norm, pos_sims, min_pos);
    k_neg<<<dim3(32, 32), 256, 0, stream>>>(xn, min_pos, sum_part, cnt_part, max_part, gmax);
    k_row<<<N / 4, 256, 0, stream>>>(sum_part, cnt_part, max_part, pos_sims, min_pos, gmax, row_loss);
    k_final<<<1, 256, 0, stream>>>(row_loss, out);
}

// Round 4
// 156.473 us; speedup vs baseline: 1.0083x; 1.0083x over previous
//
#include <hip/hip_runtime.h>
#include <hip/hip_bf16.h>
#include <math.h>

#define N 4096
#define D 1024
#define NINST 8
#define NGROUP (N / NINST)
#define ALPHA 20.0f
#define MARGIN 0.5f

typedef __attribute__((ext_vector_type(8))) short bf16x8;
typedef __attribute__((ext_vector_type(4))) float f32x4;

__device__ __forceinline__ unsigned fkey(float f) {
    int b = __float_as_int(f);
    return (b >= 0) ? ((unsigned)b | 0x80000000u) : ~(unsigned)b;
}
__device__ __forceinline__ float fdec(unsigned u) {
    int b = (u & 0x80000000u) ? (int)(u ^ 0x80000000u) : ~(int)u;
    return __int_as_float(b);
}

// stable fast softplus: log1p(exp(x)) = max(x,0) + log(1 + exp(-|x|))
__device__ __forceinline__ float softplus(float x) {
    float z = __expf(-fabsf(x));
    return fmaxf(x, 0.0f) + __logf(1.0f + z);
}

// async global -> LDS, 16 bytes per lane (lds dest: wave-uniform base + lane*16)
__device__ __forceinline__ void gld16(const void* g, void* l) {
    __builtin_amdgcn_global_load_lds(
        (const __attribute__((address_space(1))) void*)g,
        (__attribute__((address_space(3))) void*)l, 16, 0, 0);
}

// ---------------- K1: per-group normalize + bf16 write + exact fp32 8x8 Gram ----------------
// grid NGROUP(512), block 256. Each block owns 8 rows. Also zeroes gmax/accum/cnt.
__global__ __launch_bounds__(256) void k_normpos(const float* __restrict__ in,
                                                 ushort* __restrict__ xn,
                                                 float* __restrict__ pos_sims,
                                                 float* __restrict__ min_pos,
                                                 unsigned* __restrict__ gmax,
                                                 float* __restrict__ accum,
                                                 unsigned* __restrict__ cnt) {
    __shared__ float4 srows4[2048];    // 8 rows x 256 float4 = 32 KB
    __shared__ float spart[8][4];
    __shared__ float sinv[8];
    __shared__ float sg[8][8];

    int g = blockIdx.x;
    int t = threadIdx.x;
    int lane = t & 63, wid = t >> 6;

    if (g == 0 && t == 0) { *gmax = 0u; *accum = 0.f; *cnt = 0u; }

    const float4* in4 = (const float4*)in;
    #pragma unroll
    for (int i = 0; i < 8; ++i) {
        float4 v = in4[(size_t)g * 2048 + i * 256 + t];
        srows4[i * 256 + t] = v;
        float ss = v.x * v.x + v.y * v.y + v.z * v.z + v.w * v.w;
        #pragma unroll
        for (int off = 1; off < 64; off <<= 1) ss += __shfl_xor(ss, off);
        if (lane == 0) spart[i][wid] = ss;
    }
    __syncthreads();
    if (t < 8) sinv[t] = rsqrtf(spart[t][0] + spart[t][1] + spart[t][2] + spart[t][3]);
    __syncthreads();

    // bf16 normalized write
    #pragma unroll
    for (int i = 0; i < 8; ++i) {
        float4 v = srows4[i * 256 + t];
        float inv = sinv[i];
        ushort4 o;
        __hip_bfloat16 h;
        h = __float2bfloat16(v.x * inv); o.x = *(ushort*)&h;
        h = __float2bfloat16(v.y * inv); o.y = *(ushort*)&h;
        h = __float2bfloat16(v.z * inv); o.z = *(ushort*)&h;
        h = __float2bfloat16(v.w * inv); o.w = *(ushort*)&h;
        ((ushort4*)(xn + (size_t)(g * 8 + i) * D))[t] = o;
    }

    // 8x8 Gram from LDS: 64 pairs x 4 slices
    int pair = t >> 2, a = pair >> 3, b = pair & 7, slice = t & 3;
    const float4* pa = srows4 + a * 256 + slice * 64;
    const float4* pb = srows4 + b * 256 + slice * 64;
    float s = 0.f;
    #pragma unroll 8
    for (int i = 0; i < 64; ++i) {
        float4 x = pa[i], y = pb[i];
        s += x.x * y.x + x.y * y.y + x.z * y.z + x.w * y.w;
    }
    s += __shfl_xor(s, 1);
    s += __shfl_xor(s, 2);
    if (slice == 0) sg[a][b] = s * sinv[a] * sinv[b];
    __syncthreads();
    if (t < 8) {
        float mn = 1e30f;
        int idx = 0;
        #pragma unroll
        for (int b2 = 0; b2 < 8; ++b2) {
            if (b2 == t) continue;
            float v = sg[t][b2];
            mn = fminf(mn, v);
            pos_sims[(size_t)(g * 8 + t) * 8 + idx] = v;
            ++idx;
        }
        min_pos[g * 8 + t] = mn;
    }
}

// ---------------- K2: bf16 MFMA sim tiles (dbuf LDS, XCD-banded tile order) ----------------
// grid 1024; block 256 = 4 waves in 2x2; 128x128 tile; BK=32.
// XCD x (= bid & 7, HW round-robin) owns tile-rows [4x,4x+4), column-major order:
// A-panels (1 MB) stay L2-resident; B-slices shared by 4 blocks in the same L2.
__global__ __launch_bounds__(256) void k_neg(const ushort* __restrict__ xn,
                                             const float* __restrict__ min_pos,
                                             float* __restrict__ sum_part,
                                             int* __restrict__ cnt_part,
                                             float* __restrict__ max_part,
                                             unsigned* __restrict__ gmax) {
    __shared__ ushort sA[2][128 * 32];   // [buf][row][k] row-major
    __shared__ ushort sB[2][128 * 32];
    __shared__ float sMin[128];

    int bid = blockIdx.x;
    int xcd = bid & 7;
    int local = bid >> 3;              // 0..127
    int ct = local >> 2;               // 0..31  (column-major within band)
    int rt = xcd * 4 + (local & 3);    // band of 4 tile-rows per XCD

    int R0 = rt * 128, C0 = ct * 128;
    int t = threadIdx.x, lane = t & 63, wid = t >> 6;
    int wr = wid >> 1, wc = wid & 1;

    if (t < 128) sMin[t] = min_pos[R0 + t];

    int srow = t >> 2;
    int skoff = (t & 3) * 8;
    const ushort* gA0 = xn + (size_t)(R0 + srow) * D + skoff;
    const ushort* gA1 = xn + (size_t)(R0 + 64 + srow) * D + skoff;
    const ushort* gB0 = xn + (size_t)(C0 + srow) * D + skoff;
    const ushort* gB1 = xn + (size_t)(C0 + 64 + srow) * D + skoff;
    unsigned wbase = (unsigned)wid * 1024;   // 64 lanes * 16B per wave

    int lrow = lane & 15;
    int kgrp = lane >> 4;    // 0..3 -> k-octet

    f32x4 zero = {0.f, 0.f, 0.f, 0.f};
    f32x4 acc[4][4];
    #pragma unroll
    for (int m = 0; m < 4; ++m)
        #pragma unroll
        for (int n = 0; n < 4; ++n) acc[m][n] = zero;

    #define STAGE(buf, k0)                                        \
        do {                                                      \
            char* lA_ = (char*)sA[buf];                           \
            char* lB_ = (char*)sB[buf];                           \
            gld16(gA0 + (k0), lA_ + wbase);                       \
            gld16(gA1 + (k0), lA_ + 4096 + wbase);                \
            gld16(gB0 + (k0), lB_ + wbase);                       \
            gld16(gB1 + (k0), lB_ + 4096 + wbase);                \
        } while (0)

    STAGE(0, 0);
    __syncthreads();

    int cur = 0;
    for (int it = 0; it < 32; ++it) {
        if (it + 1 < 32) STAGE(cur ^ 1, (it + 1) * 32);   // prefetch next tile

        const ushort* fA = sA[cur] + (size_t)(wr * 64 + lrow) * 32 + kgrp * 8;
        const ushort* fB = sB[cur] + (size_t)(wc * 64 + lrow) * 32 + kgrp * 8;
        bf16x8 a[4], b[4];
        #pragma unroll
        for (int m = 0; m < 4; ++m)
            a[m] = *(const bf16x8*)(fA + (size_t)m * 16 * 32);
        #pragma unroll
        for (int n = 0; n < 4; ++n)
            b[n] = *(const bf16x8*)(fB + (size_t)n * 16 * 32);
        #pragma unroll
        for (int m = 0; m < 4; ++m)
            #pragma unroll
            for (int n = 0; n < 4; ++n)
                acc[m][n] = __builtin_amdgcn_mfma_f32_16x16x32_bf16(a[m], b[n], acc[m][n], 0, 0, 0);

        __syncthreads();
        cur ^= 1;
    }
    #undef STAGE

    // epilogue: per-row negative stats + global max; partials stored [row][64]
    float allmax = -1e30f;
    int pc = ct * 2 + wc;
    int cbase = C0 + wc * 64;
    #pragma unroll
    for (int m = 0; m < 4; ++m) {
        #pragma unroll
        for (int reg = 0; reg < 4; ++reg) {
            int lr = wr * 64 + m * 16 + kgrp * 4 + reg;   // local row in [0,128)
            int grow = R0 + lr;
            float th = sMin[lr] - 0.05f;
            int gi = grow >> 3;
            float rs = 0.f, rm = -1e30f;
            int rc = 0;
            #pragma unroll
            for (int n = 0; n < 4; ++n) {
                int gcol = cbase + n * 16 + lrow;
                float s = acc[m][n][reg];
                allmax = fmaxf(allmax, s);
                if ((gcol >> 3) != gi) {
                    rm = fmaxf(rm, s);
                    if (s > th) { rs += softplus(ALPHA * (s - MARGIN)); rc += 1; }
                }
            }
            #pragma unroll
            for (int off = 1; off < 16; off <<= 1) {
                rs += __shfl_xor(rs, off);
                rc += __shfl_xor(rc, off);
                rm = fmaxf(rm, __shfl_xor(rm, off));
            }
            if (lrow == 0) {
                sum_part[(size_t)grow * 64 + pc] = rs;
                cnt_part[(size_t)grow * 64 + pc] = rc;
                max_part[(size_t)grow * 64 + pc] = rm;
            }
        }
    }
    #pragma unroll
    for (int off = 1; off < 64; off <<= 1) allmax = fmaxf(allmax, __shfl_xor(allmax, off));
    if (lane == 0) atomicMax(gmax, fkey(allmax));
}

// ---------------- K3: per-row combine + last-block final mean ----------------
__global__ __launch_bounds__(256) void k_rowfinal(const float* __restrict__ sum_part,
                                                  const int* __restrict__ cnt_part,
                                                  const float* __restrict__ max_part,
                                                  const float* __restrict__ pos_sims,
                                                  const float* __restrict__ min_pos,
                                                  const unsigned* __restrict__ gmax,
                                                  float* __restrict__ accum,
                                                  unsigned* __restrict__ cnt,
                                                  float* __restrict__ out) {
    __shared__ float sloss[4];
    int row = blockIdx.x * 4 + (threadIdx.x >> 6);
    int lane = threadIdx.x & 63;
    float ns = sum_part[(size_t)row * 64 + lane];
    int nc = cnt_part[(size_t)row * 64 + lane];
    float nm = max_part[(size_t)row * 64 + lane];
    #pragma unroll
    for (int off = 1; off < 64; off <<= 1) {
        ns += __shfl_xor(ns, off);
        nc += __shfl_xor(nc, off);
        nm = fmaxf(nm, __shfl_xor(nm, off));
    }
    if (lane == 0) {
        float base = fmaxf(fdec(*gmax) - 0.1f, MARGIN + 0.2f);
        float neg_loss = (nc > 0) ? ns / (float)nc : softplus(ALPHA * (nm - MARGIN));
        float ps = 0.f;
        int pcnt = 0;
        float mn = min_pos[row];
        #pragma unroll
        for (int i = 0; i < NINST - 1; ++i) {
            float s = pos_sims[(size_t)row * 8 + i];
            if (s < base) { ps += softplus(-2.0f * (s - MARGIN)); pcnt++; }
        }
        float pos_loss = (pcnt > 0) ? ps / (float)pcnt : softplus(-2.0f * (mn - MARGIN));
        sloss[threadIdx.x >> 6] = pos_loss + neg_loss;
    }
    __syncthreads();
    if (threadIdx.x == 0) {
        float bs = sloss[0] + sloss[1] + sloss[2] + sloss[3];
        atomicAdd(accum, bs);
        __threadfence();
        unsigned old = atomicAdd(cnt, 1u);
        if (old == gridDim.x - 1) {
            __threadfence();
            float tot = atomicAdd(accum, 0.0f);   // returns final sum (all adds done)
            out[0] = tot / (float)N;
        }
    }
}

extern "C" void kernel_launch(void* const* d_in, const int* in_sizes, int n_in,
                              void* d_out, int out_size, void* d_ws, size_t ws_size,
                              hipStream_t stream) {
    const float* in = (const float*)d_in[0];
    float* out = (float*)d_out;

    char* ws = (char*)d_ws;
    ushort*  xn       = (ushort*)(ws);                          // 8 MB
    float*   min_pos  = (float*)(ws + 8388608 + 16384);         // 16 KB
    float*   pos_sims = (float*)(ws + 8388608 + 32768);         // 128 KB
    float*   sum_part = (float*)(ws + 8388608 + 32768 + 131072);            // 1 MB
    float*   max_part = (float*)(ws + 8388608 + 32768 + 131072 + 1048576);  // 1 MB
    int*     cnt_part = (int*)  (ws + 8388608 + 32768 + 131072 + 2097152);  // 1 MB
    unsigned* gmax    = (unsigned*)(ws + 8388608 + 32768 + 131072 + 3145728 + 16384);
    float*   accum    = (float*)(ws + 8388608 + 32768 + 131072 + 3145728 + 16384 + 64);
    unsigned* cnt     = (unsigned*)(ws + 8388608 + 32768 + 131072 + 3145728 + 16384 + 128);

    k_normpos<<<NGROUP, 256, 0, stream>>>(in, xn, pos_sims, min_pos, gmax, accum, cnt);
    k_neg<<<1024, 256, 0, stream>>>(xn, min_pos, sum_part, cnt_part, max_part, gmax);
    k_rowfinal<<<N / 4, 256, 0, stream>>>(sum_part, cnt_part, max_part, pos_sims, min_pos,
                                          gmax, accum, cnt, out);
}

// Round 5
// 137.097 us; speedup vs baseline: 1.1508x; 1.1413x over previous
//
#include <hip/hip_runtime.h>
#include <hip/hip_bf16.h>
#include <math.h>

#define N 4096
#define D 1024
#define NINST 8
#define NGROUP (N / NINST)
#define ALPHA 20.0f
#define MARGIN 0.5f

typedef __attribute__((ext_vector_type(8))) short bf16x8;
typedef __attribute__((ext_vector_type(4))) float f32x4;

__device__ __forceinline__ unsigned fkey(float f) {
    int b = __float_as_int(f);
    return (b >= 0) ? ((unsigned)b | 0x80000000u) : ~(unsigned)b;
}
__device__ __forceinline__ float fdec(unsigned u) {
    int b = (u & 0x80000000u) ? (int)(u ^ 0x80000000u) : ~(int)u;
    return __int_as_float(b);
}

// stable fast softplus: log1p(exp(x)) = max(x,0) + log(1 + exp(-|x|))
__device__ __forceinline__ float softplus(float x) {
    float z = __expf(-fabsf(x));
    return fmaxf(x, 0.0f) + __logf(1.0f + z);
}

// async global -> LDS, 16 bytes per lane (lds dest: wave-uniform base + lane*16)
__device__ __forceinline__ void gld16(const void* g, void* l) {
    __builtin_amdgcn_global_load_lds(
        (const __attribute__((address_space(1))) void*)g,
        (__attribute__((address_space(3))) void*)l, 16, 0, 0);
}

// ---------------- K1: per-group normalize + bf16 write + exact fp32 8x8 Gram ----------------
__global__ __launch_bounds__(256) void k_normpos(const float* __restrict__ in,
                                                 ushort* __restrict__ xn,
                                                 float* __restrict__ pos_sims,
                                                 float* __restrict__ min_pos,
                                                 unsigned* __restrict__ gmax,
                                                 float* __restrict__ accum,
                                                 unsigned* __restrict__ cnt) {
    __shared__ float4 srows4[2048];    // 8 rows x 256 float4 = 32 KB
    __shared__ float spart[8][4];
    __shared__ float sinv[8];
    __shared__ float sg[8][8];

    int g = blockIdx.x;
    int t = threadIdx.x;
    int lane = t & 63, wid = t >> 6;

    if (g == 0 && t == 0) { *gmax = 0u; *accum = 0.f; *cnt = 0u; }

    const float4* in4 = (const float4*)in;
    #pragma unroll
    for (int i = 0; i < 8; ++i) {
        float4 v = in4[(size_t)g * 2048 + i * 256 + t];
        srows4[i * 256 + t] = v;
        float ss = v.x * v.x + v.y * v.y + v.z * v.z + v.w * v.w;
        #pragma unroll
        for (int off = 1; off < 64; off <<= 1) ss += __shfl_xor(ss, off);
        if (lane == 0) spart[i][wid] = ss;
    }
    __syncthreads();
    if (t < 8) sinv[t] = rsqrtf(spart[t][0] + spart[t][1] + spart[t][2] + spart[t][3]);
    __syncthreads();

    #pragma unroll
    for (int i = 0; i < 8; ++i) {
        float4 v = srows4[i * 256 + t];
        float inv = sinv[i];
        ushort4 o;
        __hip_bfloat16 h;
        h = __float2bfloat16(v.x * inv); o.x = *(ushort*)&h;
        h = __float2bfloat16(v.y * inv); o.y = *(ushort*)&h;
        h = __float2bfloat16(v.z * inv); o.z = *(ushort*)&h;
        h = __float2bfloat16(v.w * inv); o.w = *(ushort*)&h;
        ((ushort4*)(xn + (size_t)(g * 8 + i) * D))[t] = o;
    }

    int pair = t >> 2, a = pair >> 3, b = pair & 7, slice = t & 3;
    const float4* pa = srows4 + a * 256 + slice * 64;
    const float4* pb = srows4 + b * 256 + slice * 64;
    float s = 0.f;
    #pragma unroll 8
    for (int i = 0; i < 64; ++i) {
        float4 x = pa[i], y = pb[i];
        s += x.x * y.x + x.y * y.y + x.z * y.z + x.w * y.w;
    }
    s += __shfl_xor(s, 1);
    s += __shfl_xor(s, 2);
    if (slice == 0) sg[a][b] = s * sinv[a] * sinv[b];
    __syncthreads();
    if (t < 8) {
        float mn = 1e30f;
        int idx = 0;
        #pragma unroll
        for (int b2 = 0; b2 < 8; ++b2) {
            if (b2 == t) continue;
            float v = sg[t][b2];
            mn = fminf(mn, v);
            pos_sims[(size_t)(g * 8 + t) * 8 + idx] = v;
            ++idx;
        }
        min_pos[g * 8 + t] = mn;
    }
}

// ---------------- K2: symmetric bf16 MFMA sim tiles (upper-triangular grid) ----------------
// grid 528 = 32*33/2 tiles (rt<=ct); block 256 = 4 waves in 2x2; 128x128 tile; BK=32.
// Off-diagonal tiles emit row-band stats AND col-band (transpose) stats.
// Slot map for row r in band br: slot q*2+s <- tile (q,br) col-stats (q<br, s=wr)
//                                       or   tile (br,q) row-stats (q>=br, s=wc).
__global__ __launch_bounds__(256) void k_neg(const ushort* __restrict__ xn,
                                             const float* __restrict__ min_pos,
                                             float* __restrict__ sum_part,
                                             int* __restrict__ cnt_part,
                                             float* __restrict__ max_part,
                                             unsigned* __restrict__ gmax) {
    __shared__ ushort sA[128 * 32];   // [row][k] row-major
    __shared__ ushort sB[128 * 32];
    __shared__ float sMinA[128];
    __shared__ float sMinB[128];

    // decode triangular tile index (rt, ct), ct >= rt
    int bid = blockIdx.x;
    int rt = 0, rem = bid;
    while (rem >= 32 - rt) { rem -= 32 - rt; ++rt; }
    int ct = rt + rem;
    bool diag = (rt == ct);

    int R0 = rt * 128, C0 = ct * 128;
    int t = threadIdx.x, lane = t & 63, wid = t >> 6;
    int wr = wid >> 1, wc = wid & 1;

    if (t < 128) { sMinA[t] = min_pos[R0 + t]; sMinB[t] = min_pos[C0 + t]; }

    int srow = t >> 2;
    int skoff = (t & 3) * 8;
    const ushort* gA0 = xn + (size_t)(R0 + srow) * D + skoff;
    const ushort* gA1 = xn + (size_t)(R0 + 64 + srow) * D + skoff;
    const ushort* gB0 = xn + (size_t)(C0 + srow) * D + skoff;
    const ushort* gB1 = xn + (size_t)(C0 + 64 + srow) * D + skoff;
    char* lA = (char*)sA;
    char* lB = (char*)sB;
    unsigned wbase = (unsigned)wid * 1024;   // 64 lanes * 16B per wave

    int lrow = lane & 15;
    int kgrp = lane >> 4;    // 0..3 -> k-octet

    f32x4 zero = {0.f, 0.f, 0.f, 0.f};
    f32x4 acc[4][4];
    #pragma unroll
    for (int m = 0; m < 4; ++m)
        #pragma unroll
        for (int n = 0; n < 4; ++n) acc[m][n] = zero;

    const ushort* sBbase = diag ? sA : sB;
    const ushort* fA = sA + (size_t)(wr * 64 + lrow) * 32 + kgrp * 8;
    const ushort* fB = sBbase + (size_t)(wc * 64 + lrow) * 32 + kgrp * 8;

    for (int k0 = 0; k0 < D; k0 += 32) {
        __syncthreads();   // previous tile's reads complete before overwrite
        gld16(gA0 + k0, lA + wbase);
        gld16(gA1 + k0, lA + 4096 + wbase);
        if (!diag) {
            gld16(gB0 + k0, lB + wbase);
            gld16(gB1 + k0, lB + 4096 + wbase);
        }
        __syncthreads();   // staged data visible

        bf16x8 a[4], b[4];
        #pragma unroll
        for (int m = 0; m < 4; ++m)
            a[m] = *(const bf16x8*)(fA + (size_t)m * 16 * 32);
        #pragma unroll
        for (int n = 0; n < 4; ++n)
            b[n] = *(const bf16x8*)(fB + (size_t)n * 16 * 32);
        #pragma unroll
        for (int m = 0; m < 4; ++m)
            #pragma unroll
            for (int n = 0; n < 4; ++n)
                acc[m][n] = __builtin_amdgcn_mfma_f32_16x16x32_bf16(a[m], b[n], acc[m][n], 0, 0, 0);
    }

    // ---- epilogue ----
    float allmax = -1e30f;
    int cbase = C0 + wc * 64;
    int pcRow = ct * 2 + wc;     // row-stat slot
    int pcCol = rt * 2 + wr;     // col-stat slot (transpose contribution)

    float thB[4];
    #pragma unroll
    for (int n = 0; n < 4; ++n) thB[n] = sMinB[wc * 64 + n * 16 + lrow] - 0.05f;

    float colS[4] = {0.f, 0.f, 0.f, 0.f};
    float colM[4] = {-1e30f, -1e30f, -1e30f, -1e30f};
    int   colC[4] = {0, 0, 0, 0};

    #pragma unroll
    for (int m = 0; m < 4; ++m) {
        #pragma unroll
        for (int reg = 0; reg < 4; ++reg) {
            int lr = wr * 64 + m * 16 + kgrp * 4 + reg;   // local row in [0,128)
            int grow = R0 + lr;
            float th = sMinA[lr] - 0.05f;
            int gi = grow >> 3;
            float rs = 0.f, rm = -1e30f;
            int rc = 0;
            #pragma unroll
            for (int n = 0; n < 4; ++n) {
                int gcol = cbase + n * 16 + lrow;
                float s = acc[m][n][reg];
                allmax = fmaxf(allmax, s);
                if ((gcol >> 3) != gi) {
                    float e = softplus(ALPHA * (s - MARGIN));
                    // row-band stats (reduce over cols)
                    rm = fmaxf(rm, s);
                    if (s > th) { rs += e; rc += 1; }
                    // col-band stats (transpose rows), off-diagonal only
                    if (!diag) {
                        colM[n] = fmaxf(colM[n], s);
                        if (s > thB[n]) { colS[n] += e; colC[n] += 1; }
                    }
                }
            }
            #pragma unroll
            for (int off = 1; off < 16; off <<= 1) {
                rs += __shfl_xor(rs, off);
                rc += __shfl_xor(rc, off);
                rm = fmaxf(rm, __shfl_xor(rm, off));
            }
            if (lrow == 0) {
                sum_part[(size_t)grow * 64 + pcRow] = rs;
                cnt_part[(size_t)grow * 64 + pcRow] = rc;
                max_part[(size_t)grow * 64 + pcRow] = rm;
            }
        }
    }

    if (!diag) {
        // reduce col stats across the 4 kgrp lane-groups (lanes l, l^16, l^32, l^48)
        #pragma unroll
        for (int n = 0; n < 4; ++n) {
            float cs = colS[n], cm = colM[n];
            int cc = colC[n];
            cs += __shfl_xor(cs, 16); cs += __shfl_xor(cs, 32);
            cc += __shfl_xor(cc, 16); cc += __shfl_xor(cc, 32);
            cm = fmaxf(cm, __shfl_xor(cm, 16));
            cm = fmaxf(cm, __shfl_xor(cm, 32));
            if (kgrp == 0) {
                int gcol = cbase + n * 16 + lrow;
                sum_part[(size_t)gcol * 64 + pcCol] = cs;
                cnt_part[(size_t)gcol * 64 + pcCol] = cc;
                max_part[(size_t)gcol * 64 + pcCol] = cm;
            }
        }
    }

    #pragma unroll
    for (int off = 1; off < 64; off <<= 1) allmax = fmaxf(allmax, __shfl_xor(allmax, off));
    if (lane == 0) atomicMax(gmax, fkey(allmax));
}

// ---------------- K3: per-row combine + last-block final mean ----------------
__global__ __launch_bounds__(256) void k_rowfinal(const float* __restrict__ sum_part,
                                                  const int* __restrict__ cnt_part,
                                                  const float* __restrict__ max_part,
                                                  const float* __restrict__ pos_sims,
                                                  const float* __restrict__ min_pos,
                                                  const unsigned* __restrict__ gmax,
                                                  float* __restrict__ accum,
                                                  unsigned* __restrict__ cnt,
                                                  float* __restrict__ out) {
    __shared__ float sloss[4];
    int row = blockIdx.x * 4 + (threadIdx.x >> 6);
    int lane = threadIdx.x & 63;
    float ns = sum_part[(size_t)row * 64 + lane];
    int nc = cnt_part[(size_t)row * 64 + lane];
    float nm = max_part[(size_t)row * 64 + lane];
    #pragma unroll
    for (int off = 1; off < 64; off <<= 1) {
        ns += __shfl_xor(ns, off);
        nc += __shfl_xor(nc, off);
        nm = fmaxf(nm, __shfl_xor(nm, off));
    }
    if (lane == 0) {
        float base = fmaxf(fdec(*gmax) - 0.1f, MARGIN + 0.2f);
        float neg_loss = (nc > 0) ? ns / (float)nc : softplus(ALPHA * (nm - MARGIN));
        float ps = 0.f;
        int pcnt = 0;
        float mn = min_pos[row];
        #pragma unroll
        for (int i = 0; i < NINST - 1; ++i) {
            float s = pos_sims[(size_t)row * 8 + i];
            if (s < base) { ps += softplus(-2.0f * (s - MARGIN)); pcnt++; }
        }
        float pos_loss = (pcnt > 0) ? ps / (float)pcnt : softplus(-2.0f * (mn - MARGIN));
        sloss[threadIdx.x >> 6] = pos_loss + neg_loss;
    }
    __syncthreads();
    if (threadIdx.x == 0) {
        float bs = sloss[0] + sloss[1] + sloss[2] + sloss[3];
        atomicAdd(accum, bs);
        __threadfence();
        unsigned old = atomicAdd(cnt, 1u);
        if (old == gridDim.x - 1) {
            __threadfence();
            float tot = atomicAdd(accum, 0.0f);   // final sum (all adds done)
            out[0] = tot / (float)N;
        }
    }
}

extern "C" void kernel_launch(void* const* d_in, const int* in_sizes, int n_in,
                              void* d_out, int out_size, void* d_ws, size_t ws_size,
                              hipStream_t stream) {
    const float* in = (const float*)d_in[0];
    float* out = (float*)d_out;

    char* ws = (char*)d_ws;
    ushort*  xn       = (ushort*)(ws);                          // 8 MB
    float*   min_pos  = (float*)(ws + 8388608 + 16384);         // 16 KB
    float*   pos_sims = (float*)(ws + 8388608 + 32768);         // 128 KB
    float*   sum_part = (float*)(ws + 8388608 + 32768 + 131072);            // 1 MB
    float*   max_part = (float*)(ws + 8388608 + 32768 + 131072 + 1048576);  // 1 MB
    int*     cnt_part = (int*)  (ws + 8388608 + 32768 + 131072 + 2097152);  // 1 MB
    unsigned* gmax    = (unsigned*)(ws + 8388608 + 32768 + 131072 + 3145728 + 16384);
    float*   accum    = (float*)(ws + 8388608 + 32768 + 131072 + 3145728 + 16384 + 64);
    unsigned* cnt     = (unsigned*)(ws + 8388608 + 32768 + 131072 + 3145728 + 16384 + 128);

    k_normpos<<<NGROUP, 256, 0, stream>>>(in, xn, pos_sims, min_pos, gmax, accum, cnt);
    k_neg<<<528, 256, 0, stream>>>(xn, min_pos, sum_part, cnt_part, max_part, gmax);
    k_rowfinal<<<N / 4, 256, 0, stream>>>(sum_part, cnt_part, max_part, pos_sims, min_pos,
                                          gmax, accum, cnt, out);
}